// Round 15
// baseline (411.920 us; speedup 1.0000x reference)
//
#include <hip/hip_runtime.h>

#define NB 4
#define NN 256
#define NH 128
#define LN_EPS 1e-5f

typedef float f32x2 __attribute__((ext_vector_type(2)));

__device__ __forceinline__ float elu1(float x){
  return x > 0.f ? x : (__expf(x) - 1.f);
}

// K0a: lin_in = v@W_in.T + b_in ; lin_out = v@W_out.T + b_out (fp32 exact).
// Also zeroes out_v (used as the agg accumulator by the main kernel).
__global__ __launch_bounds__(128) void lin_vw_kernel(
    const float* __restrict__ v,
    const float* __restrict__ W_in, const float* __restrict__ b_in,
    const float* __restrict__ W_out, const float* __restrict__ b_out,
    float* __restrict__ lin_in, float* __restrict__ lin_out,
    float* __restrict__ out_v)
{
  const int row = blockIdx.x;    // b*NN + i
  const int t = threadIdx.x;     // output col
  __shared__ float vs[NH];
  vs[t] = v[(size_t)row*NH + t];
  out_v[(size_t)row*NH + t] = 0.f;   // zero agg accumulator
  __syncthreads();
  const float4* wi = (const float4*)(W_in + t*NH);
  const float4* wo = (const float4*)(W_out + t*NH);
  const float4* vv = (const float4*)vs;
  float ai = b_in[t], ao = b_out[t];
  #pragma unroll
  for (int k = 0; k < NH/4; ++k){
    float4 x = vv[k];
    float4 a = wi[k], bq = wo[k];
    ai += x.x*a.x + x.y*a.y + x.z*a.z + x.w*a.w;
    ao += x.x*bq.x + x.y*bq.y + x.z*bq.z + x.w*bq.w;
  }
  lin_in[(size_t)row*NH + t]  = ai;
  lin_out[(size_t)row*NH + t] = ao;
}

// K0b: Wt_g[k][c] = W_e2e[c][k]
__global__ __launch_bounds__(128) void transpose_w_kernel(
    const float* __restrict__ W, float* __restrict__ Wt)
{
  const int c = blockIdx.x;
  const int k = threadIdx.x;
  Wt[(size_t)k*NH + c] = W[(size_t)c*NH + k];
}

#define LD4(p) (*(const float4*)(p))

// Main: grid = 2048; block (half, b, j) handles i in [half*128, half*128+128).
// NO LDS in the hot loop, NO barriers: e read as wave-uniform global
// broadcasts (L1/L2-served), W from pre-transposed global (L2-resident).
// Lane owns 2 cols x 8 rows; f32x2 acc (v_pk_fma_f32). 8 blocks/CU resident.
// Writes e_out; atomicAdds 128 agg partials into out_v (zeroed by K0a).
__global__ __launch_bounds__(256) void nri_eout_kernel(
    const float* __restrict__ e,
    const int* __restrict__ e_mask,
    const float* __restrict__ Wt_g,  const float* __restrict__ b_e2e,
    const float* __restrict__ g_e,   const float* __restrict__ be_e,
    const float* __restrict__ lin_in, const float* __restrict__ lin_out,
    float* __restrict__ out_e, float* __restrict__ out_v)
{
  const int blk  = blockIdx.x;
  const int half = blk >> 10;          // 0 or 1
  const int bj   = blk & 1023;
  const int b    = bj >> 8, j = bj & (NN-1);
  const int ibeg = half * 128;
  const int tid  = threadIdx.x;
  const int wave = tid >> 6;
  const int l    = tid & 63;
  const int c0   = 2*l;

  __shared__ float aggl[4][NH];     // 2 KB (epilogue only)

  const float* lo = lin_out + (size_t)(b*NN + j)*NH;
  f32x2 bj2, gc2, bec2;
  bj2.x  = lo[c0]   + b_e2e[c0];
  bj2.y  = lo[c0+1] + b_e2e[c0+1];
  gc2.x  = g_e[c0];  gc2.y  = g_e[c0+1];
  bec2.x = be_e[c0]; bec2.y = be_e[c0+1];

  f32x2 agg = {0.f, 0.f};

  const size_t ebase   = ((size_t)b*NN)*NN*NH + (size_t)j*NH;
  const size_t estride = (size_t)NN*NH;
  const int*   emcol   = e_mask + (size_t)(b*NN)*NN + j;
  const int    srow    = 8*wave;       // this wave's 8 rows within the tile

  for (int t = 0; t < 4; ++t){
    const int i0 = ibeg + 32*t + srow;

    // wave-uniform row pointers (broadcast loads, L1/L2-served)
    const float* er[8];
    #pragma unroll
    for (int r = 0; r < 8; ++r)
      er[r] = e + ebase + (size_t)(i0 + r)*estride;

    f32x2 acc[8];
    #pragma unroll
    for (int r = 0; r < 8; ++r) acc[r] = (f32x2){0.f, 0.f};

    for (int k = 0; k < NH; k += 4){
      const f32x2 w0 = *(const f32x2*)(Wt_g + (size_t)(k+0)*NH + c0);
      const f32x2 w1 = *(const f32x2*)(Wt_g + (size_t)(k+1)*NH + c0);
      const f32x2 w2 = *(const f32x2*)(Wt_g + (size_t)(k+2)*NH + c0);
      const f32x2 w3 = *(const f32x2*)(Wt_g + (size_t)(k+3)*NH + c0);
      #pragma unroll
      for (int r = 0; r < 8; ++r){
        const float4 ev = LD4(er[r] + k);                 // 64-lane broadcast
        acc[r] += w0*ev.x + w1*ev.y + w2*ev.z + w3*ev.w;  // v_pk_fma_f32
      }
    }

    #pragma unroll
    for (int r = 0; r < 8; ++r){
      const int i = i0 + r;
      const f32x2 li = *(const f32x2*)(lin_in + (size_t)(b*NN + i)*NH + c0);
      const f32x2 x = acc[r] + li + bj2;
      float s  = x.x + x.y;
      float s2 = x.x*x.x + x.y*x.y;
      #pragma unroll
      for (int m = 1; m <= 32; m <<= 1){
        s  += __shfl_xor(s,  m, 64);
        s2 += __shfl_xor(s2, m, 64);
      }
      const float mu  = s * (1.f/NH);
      const float var = s2 * (1.f/NH) - mu*mu;
      const float rs  = rsqrtf(var + LN_EPS);
      const int zf = (i == j) || emcol[(size_t)i*NN];
      f32x2 hh;
      hh.x = zf ? 0.f : elu1((x.x - mu)*rs*gc2.x + bec2.x);
      hh.y = zf ? 0.f : elu1((x.y - mu)*rs*gc2.y + bec2.y);
      *(f32x2*)(out_e + ebase + (size_t)i*estride + c0) = hh;
      agg += hh;
    }
  }

  // block partial agg -> atomicAdd into out_v (zero-initialized by K0a)
  aggl[wave][c0]   = agg.x;
  aggl[wave][c0+1] = agg.y;
  __syncthreads();
  if (tid < NH){
    const float a = aggl[0][tid] + aggl[1][tid] + aggl[2][tid] + aggl[3][tid];
    atomicAdd(&out_v[(size_t)bj*NH + tid], a);
  }
}

// Combine (in place): out_v currently holds agg; finalize to
// out_v = masked v + elu(LN(agg)).
__global__ __launch_bounds__(128) void vnew_combine_kernel(
    const float* __restrict__ v,
    const int* __restrict__ v_mask,
    const float* __restrict__ g_v, const float* __restrict__ be_v,
    float* __restrict__ out_v)
{
  const int bj = blockIdx.x;   // b*NN + j
  const int c  = threadIdx.x;  // 0..127

  const float a = out_v[(size_t)bj*NH + c];

  __shared__ float red[4];
  float s = a, s2 = a*a;
  #pragma unroll
  for (int m = 1; m <= 32; m <<= 1){
    s  += __shfl_xor(s,  m, 64);
    s2 += __shfl_xor(s2, m, 64);
  }
  const int w = c >> 6;
  if ((c & 63) == 0){ red[w*2] = s; red[w*2+1] = s2; }
  __syncthreads();
  s  = red[0] + red[2];
  s2 = red[1] + red[3];

  const float mu  = s * (1.f/NH);
  const float var = s2 * (1.f/NH) - mu*mu;
  const float rs  = rsqrtf(var + LN_EPS);
  const float h   = elu1((a - mu)*rs*g_v[c] + be_v[c]);
  const int vm = v_mask[bj];
  const float vv = vm ? 0.f : v[(size_t)bj*NH + c];
  out_v[(size_t)bj*NH + c] = vv + h;
}

extern "C" void kernel_launch(void* const* d_in, const int* in_sizes, int n_in,
                              void* d_out, int out_size, void* d_ws, size_t ws_size,
                              hipStream_t stream)
{
  const float* v      = (const float*)d_in[0];
  const float* e      = (const float*)d_in[1];
  const int*   v_mask = (const int*)d_in[2];
  const int*   e_mask = (const int*)d_in[3];
  const float* W_in   = (const float*)d_in[4];
  const float* b_in   = (const float*)d_in[5];
  const float* W_out  = (const float*)d_in[6];
  const float* b_out  = (const float*)d_in[7];
  const float* W_e2e  = (const float*)d_in[8];
  const float* b_e2e  = (const float*)d_in[9];
  const float* g_e    = (const float*)d_in[10];
  const float* be_e   = (const float*)d_in[11];
  const float* g_v    = (const float*)d_in[12];
  const float* be_v   = (const float*)d_in[13];

  // ws layout: byte-identical to the round-12/14 proven-safe footprint.
  float* lin_in  = (float*)d_ws;                 // [NB*NN, NH]  512 KB
  float* lin_out = lin_in + NB*NN*NH;            // [NB*NN, NH]  512 KB
  float* Wt_g    = lin_out + NB*NN*NH;           // [NH, NH]      64 KB

  float* out_v = (float*)d_out;                  // [NB,NN,NH]
  float* out_e = out_v + (size_t)NB*NN*NH;       // [NB,NN,NN,NH]

  lin_vw_kernel<<<NB*NN, NH, 0, stream>>>(v, W_in, b_in, W_out, b_out,
                                          lin_in, lin_out, out_v);
  transpose_w_kernel<<<NH, NH, 0, stream>>>(W_e2e, Wt_g);
  nri_eout_kernel<<<2*NB*NN, 256, 0, stream>>>(e, e_mask,
                                               Wt_g, b_e2e, g_e, be_e,
                                               lin_in, lin_out,
                                               out_e, out_v);
  vnew_combine_kernel<<<NB*NN, 128, 0, stream>>>(v, v_mask, g_v, be_v, out_v);
}

// Round 16
// 246.502 us; speedup vs baseline: 1.6711x; 1.6711x over previous
//
#include <hip/hip_runtime.h>

#define NB 4
#define NN 256
#define NH 128
#define LN_EPS 1e-5f

typedef float f32x2 __attribute__((ext_vector_type(2)));

__device__ __forceinline__ float elu1(float x){
  return x > 0.f ? x : (__expf(x) - 1.f);
}

// K0a: lin_in = v@W_in.T + b_in ; lin_out = v@W_out.T + b_out (fp32 exact).
// Also zeroes out_v (agg accumulator for the main kernel's atomics).
__global__ __launch_bounds__(128) void lin_vw_kernel(
    const float* __restrict__ v,
    const float* __restrict__ W_in, const float* __restrict__ b_in,
    const float* __restrict__ W_out, const float* __restrict__ b_out,
    float* __restrict__ lin_in, float* __restrict__ lin_out,
    float* __restrict__ out_v)
{
  const int row = blockIdx.x;    // b*NN + i
  const int t = threadIdx.x;     // output col
  __shared__ float vs[NH];
  vs[t] = v[(size_t)row*NH + t];
  out_v[(size_t)row*NH + t] = 0.f;   // zero agg accumulator
  __syncthreads();
  const float4* wi = (const float4*)(W_in + t*NH);
  const float4* wo = (const float4*)(W_out + t*NH);
  const float4* vv = (const float4*)vs;
  float ai = b_in[t], ao = b_out[t];
  #pragma unroll
  for (int k = 0; k < NH/4; ++k){
    float4 x = vv[k];
    float4 a = wi[k], bq = wo[k];
    ai += x.x*a.x + x.y*a.y + x.z*a.z + x.w*a.w;
    ao += x.x*bq.x + x.y*bq.y + x.z*bq.z + x.w*bq.w;
  }
  lin_in[(size_t)row*NH + t]  = ai;
  lin_out[(size_t)row*NH + t] = ao;
}

// K0b: Wt_g[k][c] = W_e2e[c][k]
__global__ __launch_bounds__(128) void transpose_w_kernel(
    const float* __restrict__ W, float* __restrict__ Wt)
{
  const int c = blockIdx.x;
  const int k = threadIdx.x;
  Wt[(size_t)k*NH + c] = W[(size_t)c*NH + k];
}

#define LD4(p) (*(const float4*)(p))

// Main: grid = 2048; block (half, b, j) handles i in [half*128, half*128+128).
// LDS-staged e tile (coalesced loads, async split), lane = 2 cols, f32x2 acc
// (v_pk_fma_f32). VGPR pinned <=64 via launch_bounds(256,8): 8 blocks/CU AND
// 8 waves/SIMD. Per-wave agg partials atomicAdd'ed directly into out_v.
__global__ __launch_bounds__(256, 8) void nri_eout_kernel(
    const float* __restrict__ e,
    const int* __restrict__ e_mask,
    const float* __restrict__ Wt_g,  const float* __restrict__ b_e2e,
    const float* __restrict__ g_e,   const float* __restrict__ be_e,
    const float* __restrict__ lin_in, const float* __restrict__ lin_out,
    float* __restrict__ out_e, float* __restrict__ out_v)
{
  const int blk  = blockIdx.x;
  const int half = blk >> 10;          // 0 or 1
  const int bj   = blk & 1023;
  const int b    = bj >> 8, j = bj & (NN-1);
  const int ibeg = half * 128;
  const int tid  = threadIdx.x;
  const int wave = tid >> 6;
  const int l    = tid & 63;
  const int c0   = 2*l;

  __shared__ float etile[32][NH];   // 16 KB, the only LDS

  const float* lo = lin_out + (size_t)(b*NN + j)*NH;
  f32x2 bj2, gc2, bec2;
  bj2.x  = lo[c0]   + b_e2e[c0];
  bj2.y  = lo[c0+1] + b_e2e[c0+1];
  gc2.x  = g_e[c0];  gc2.y  = g_e[c0+1];
  bec2.x = be_e[c0]; bec2.y = be_e[c0+1];

  f32x2 agg = {0.f, 0.f};

  const size_t ebase   = ((size_t)b*NN)*NN*NH + (size_t)j*NH;
  const size_t estride = (size_t)NN*NH;
  const int*   emcol   = e_mask + (size_t)(b*NN)*NN + j;

  const int srow  = 8*wave;
  const int scol  = (l & 31) * 4;
  const int shalf = l >> 5;
  float4 st0, st1, st2, st3;

  #define STAGE_LOAD(i0_) { \
    const float* sb = e + ebase + scol; \
    st0 = LD4(sb + (size_t)((i0_) + srow + 0 + shalf)*estride); \
    st1 = LD4(sb + (size_t)((i0_) + srow + 2 + shalf)*estride); \
    st2 = LD4(sb + (size_t)((i0_) + srow + 4 + shalf)*estride); \
    st3 = LD4(sb + (size_t)((i0_) + srow + 6 + shalf)*estride); }

  #define STAGE_WRITE() { \
    *(float4*)&etile[srow + 0 + shalf][scol] = st0; \
    *(float4*)&etile[srow + 2 + shalf][scol] = st1; \
    *(float4*)&etile[srow + 4 + shalf][scol] = st2; \
    *(float4*)&etile[srow + 6 + shalf][scol] = st3; }

  STAGE_LOAD(ibeg)
  STAGE_WRITE()
  __syncthreads();

  for (int t = 0; t < 4; ++t){
    const int i0 = ibeg + 32*t;
    if (t < 3) STAGE_LOAD(i0 + 32)   // in flight across the compute phase

    f32x2 acc[8];
    #pragma unroll
    for (int r = 0; r < 8; ++r) acc[r] = (f32x2){0.f, 0.f};

    for (int k = 0; k < NH; k += 4){
      const f32x2 w0 = *(const f32x2*)(Wt_g + (size_t)(k+0)*NH + c0);
      const f32x2 w1 = *(const f32x2*)(Wt_g + (size_t)(k+1)*NH + c0);
      const f32x2 w2 = *(const f32x2*)(Wt_g + (size_t)(k+2)*NH + c0);
      const f32x2 w3 = *(const f32x2*)(Wt_g + (size_t)(k+3)*NH + c0);
      #pragma unroll
      for (int r = 0; r < 8; ++r){
        const float4 ev = *(const float4*)&etile[srow + r][k];  // broadcast
        acc[r] += w0*ev.x + w1*ev.y + w2*ev.z + w3*ev.w;        // v_pk_fma_f32
      }
    }

    #pragma unroll
    for (int r = 0; r < 8; ++r){
      const int i = i0 + srow + r;
      const f32x2 li = *(const f32x2*)(lin_in + (size_t)(b*NN + i)*NH + c0);
      const f32x2 x = acc[r] + li + bj2;
      float s  = x.x + x.y;
      float s2 = x.x*x.x + x.y*x.y;
      #pragma unroll
      for (int m = 1; m <= 32; m <<= 1){
        s  += __shfl_xor(s,  m, 64);
        s2 += __shfl_xor(s2, m, 64);
      }
      const float mu  = s * (1.f/NH);
      const float var = s2 * (1.f/NH) - mu*mu;
      const float rs  = rsqrtf(var + LN_EPS);
      const int zf = (i == j) || emcol[(size_t)i*NN];
      f32x2 hh;
      hh.x = zf ? 0.f : elu1((x.x - mu)*rs*gc2.x + bec2.x);
      hh.y = zf ? 0.f : elu1((x.y - mu)*rs*gc2.y + bec2.y);
      *(f32x2*)(out_e + ebase + (size_t)i*estride + c0) = hh;
      agg += hh;
    }

    __syncthreads();
    if (t < 3){ STAGE_WRITE() }
    __syncthreads();
  }

  // per-wave agg partials -> atomicAdd into out_v (zeroed by K0a).
  // 8 atomics per element total (4 waves x 2 halves) - deterministic enough
  // (fp32 order noise ~ulp, validated protocol in round 14).
  atomicAdd(&out_v[(size_t)bj*NH + c0],     agg.x);
  atomicAdd(&out_v[(size_t)bj*NH + c0 + 1], agg.y);
}

// Combine (in place): out_v currently holds agg; finalize to
// out_v = masked v + elu(LN(agg)).
__global__ __launch_bounds__(128) void vnew_combine_kernel(
    const float* __restrict__ v,
    const int* __restrict__ v_mask,
    const float* __restrict__ g_v, const float* __restrict__ be_v,
    float* __restrict__ out_v)
{
  const int bj = blockIdx.x;   // b*NN + j
  const int c  = threadIdx.x;  // 0..127

  const float a = out_v[(size_t)bj*NH + c];

  __shared__ float red[4];
  float s = a, s2 = a*a;
  #pragma unroll
  for (int m = 1; m <= 32; m <<= 1){
    s  += __shfl_xor(s,  m, 64);
    s2 += __shfl_xor(s2, m, 64);
  }
  const int w = c >> 6;
  if ((c & 63) == 0){ red[w*2] = s; red[w*2+1] = s2; }
  __syncthreads();
  s  = red[0] + red[2];
  s2 = red[1] + red[3];

  const float mu  = s * (1.f/NH);
  const float var = s2 * (1.f/NH) - mu*mu;
  const float rs  = rsqrtf(var + LN_EPS);
  const float h   = elu1((a - mu)*rs*g_v[c] + be_v[c]);
  const int vm = v_mask[bj];
  const float vv = vm ? 0.f : v[(size_t)bj*NH + c];
  out_v[(size_t)bj*NH + c] = vv + h;
}

extern "C" void kernel_launch(void* const* d_in, const int* in_sizes, int n_in,
                              void* d_out, int out_size, void* d_ws, size_t ws_size,
                              hipStream_t stream)
{
  const float* v      = (const float*)d_in[0];
  const float* e      = (const float*)d_in[1];
  const int*   v_mask = (const int*)d_in[2];
  const int*   e_mask = (const int*)d_in[3];
  const float* W_in   = (const float*)d_in[4];
  const float* b_in   = (const float*)d_in[5];
  const float* W_out  = (const float*)d_in[6];
  const float* b_out  = (const float*)d_in[7];
  const float* W_e2e  = (const float*)d_in[8];
  const float* b_e2e  = (const float*)d_in[9];
  const float* g_e    = (const float*)d_in[10];
  const float* be_e   = (const float*)d_in[11];
  const float* g_v    = (const float*)d_in[12];
  const float* be_v   = (const float*)d_in[13];

  // ws layout: byte-identical to the round-12/14 proven-safe footprint.
  float* lin_in  = (float*)d_ws;                 // [NB*NN, NH]  512 KB
  float* lin_out = lin_in + NB*NN*NH;            // [NB*NN, NH]  512 KB
  float* Wt_g    = lin_out + NB*NN*NH;           // [NH, NH]      64 KB

  float* out_v = (float*)d_out;                  // [NB,NN,NH]
  float* out_e = out_v + (size_t)NB*NN*NH;       // [NB,NN,NN,NH]

  lin_vw_kernel<<<NB*NN, NH, 0, stream>>>(v, W_in, b_in, W_out, b_out,
                                          lin_in, lin_out, out_v);
  transpose_w_kernel<<<NH, NH, 0, stream>>>(W_e2e, Wt_g);
  nri_eout_kernel<<<2*NB*NN, 256, 0, stream>>>(e, e_mask,
                                               Wt_g, b_e2e, g_e, be_e,
                                               lin_in, lin_out,
                                               out_e, out_v);
  vnew_combine_kernel<<<NB*NN, 128, 0, stream>>>(v, v_mask, g_v, be_v, out_v);
}

// Round 17
// 245.021 us; speedup vs baseline: 1.6812x; 1.0060x over previous
//
#include <hip/hip_runtime.h>

#define NB 4
#define NN 256
#define NH 128
#define LN_EPS 1e-5f

typedef float f32x2 __attribute__((ext_vector_type(2)));

__device__ __forceinline__ float elu1(float x){
  return x > 0.f ? x : (__expf(x) - 1.f);
}

// K0a: lin_in = v@W_in.T + b_in ; lin_out = v@W_out.T + b_out (fp32 exact).
// Also zeroes out_v (agg accumulator for the main kernel's atomics).
__global__ __launch_bounds__(128) void lin_vw_kernel(
    const float* __restrict__ v,
    const float* __restrict__ W_in, const float* __restrict__ b_in,
    const float* __restrict__ W_out, const float* __restrict__ b_out,
    float* __restrict__ lin_in, float* __restrict__ lin_out,
    float* __restrict__ out_v)
{
  const int row = blockIdx.x;    // b*NN + i
  const int t = threadIdx.x;     // output col
  __shared__ float vs[NH];
  vs[t] = v[(size_t)row*NH + t];
  out_v[(size_t)row*NH + t] = 0.f;   // zero agg accumulator
  __syncthreads();
  const float4* wi = (const float4*)(W_in + t*NH);
  const float4* wo = (const float4*)(W_out + t*NH);
  const float4* vv = (const float4*)vs;
  float ai = b_in[t], ao = b_out[t];
  #pragma unroll
  for (int k = 0; k < NH/4; ++k){
    float4 x = vv[k];
    float4 a = wi[k], bq = wo[k];
    ai += x.x*a.x + x.y*a.y + x.z*a.z + x.w*a.w;
    ao += x.x*bq.x + x.y*bq.y + x.z*bq.z + x.w*bq.w;
  }
  lin_in[(size_t)row*NH + t]  = ai;
  lin_out[(size_t)row*NH + t] = ao;
}

// K0b: Wt_g[k][c] = W_e2e[c][k]
__global__ __launch_bounds__(128) void transpose_w_kernel(
    const float* __restrict__ W, float* __restrict__ Wt)
{
  const int c = blockIdx.x;
  const int k = threadIdx.x;
  Wt[(size_t)k*NH + c] = W[(size_t)c*NH + k];
}

#define LD4(p) (*(const float4*)(p))

// Main: grid = 2048; block (half, b, j) handles i in [half*128, half*128+128).
// LDS-staged e tile (coalesced loads, async split), lane = 2 cols, f32x2 acc
// (v_pk_fma_f32). VGPR pinned <=64 via launch_bounds(256,8): 8 blocks/CU AND
// 8 waves/SIMD. Per-wave agg partials atomicAdd'ed directly into out_v.
__global__ __launch_bounds__(256, 8) void nri_eout_kernel(
    const float* __restrict__ e,
    const int* __restrict__ e_mask,
    const float* __restrict__ Wt_g,  const float* __restrict__ b_e2e,
    const float* __restrict__ g_e,   const float* __restrict__ be_e,
    const float* __restrict__ lin_in, const float* __restrict__ lin_out,
    float* __restrict__ out_e, float* __restrict__ out_v)
{
  const int blk  = blockIdx.x;
  const int half = blk >> 10;          // 0 or 1
  const int bj   = blk & 1023;
  const int b    = bj >> 8, j = bj & (NN-1);
  const int ibeg = half * 128;
  const int tid  = threadIdx.x;
  const int wave = tid >> 6;
  const int l    = tid & 63;
  const int c0   = 2*l;

  __shared__ float etile[32][NH];   // 16 KB, the only LDS

  const float* lo = lin_out + (size_t)(b*NN + j)*NH;
  f32x2 bj2, gc2, bec2;
  bj2.x  = lo[c0]   + b_e2e[c0];
  bj2.y  = lo[c0+1] + b_e2e[c0+1];
  gc2.x  = g_e[c0];  gc2.y  = g_e[c0+1];
  bec2.x = be_e[c0]; bec2.y = be_e[c0+1];

  f32x2 agg = {0.f, 0.f};

  const size_t ebase   = ((size_t)b*NN)*NN*NH + (size_t)j*NH;
  const size_t estride = (size_t)NN*NH;
  const int*   emcol   = e_mask + (size_t)(b*NN)*NN + j;

  const int srow  = 8*wave;
  const int scol  = (l & 31) * 4;
  const int shalf = l >> 5;
  float4 st0, st1, st2, st3;

  #define STAGE_LOAD(i0_) { \
    const float* sb = e + ebase + scol; \
    st0 = LD4(sb + (size_t)((i0_) + srow + 0 + shalf)*estride); \
    st1 = LD4(sb + (size_t)((i0_) + srow + 2 + shalf)*estride); \
    st2 = LD4(sb + (size_t)((i0_) + srow + 4 + shalf)*estride); \
    st3 = LD4(sb + (size_t)((i0_) + srow + 6 + shalf)*estride); }

  #define STAGE_WRITE() { \
    *(float4*)&etile[srow + 0 + shalf][scol] = st0; \
    *(float4*)&etile[srow + 2 + shalf][scol] = st1; \
    *(float4*)&etile[srow + 4 + shalf][scol] = st2; \
    *(float4*)&etile[srow + 6 + shalf][scol] = st3; }

  STAGE_LOAD(ibeg)
  STAGE_WRITE()
  __syncthreads();

  for (int t = 0; t < 4; ++t){
    const int i0 = ibeg + 32*t;
    if (t < 3) STAGE_LOAD(i0 + 32)   // in flight across the compute phase

    f32x2 acc[8];
    #pragma unroll
    for (int r = 0; r < 8; ++r) acc[r] = (f32x2){0.f, 0.f};

    for (int k = 0; k < NH; k += 4){
      const f32x2 w0 = *(const f32x2*)(Wt_g + (size_t)(k+0)*NH + c0);
      const f32x2 w1 = *(const f32x2*)(Wt_g + (size_t)(k+1)*NH + c0);
      const f32x2 w2 = *(const f32x2*)(Wt_g + (size_t)(k+2)*NH + c0);
      const f32x2 w3 = *(const f32x2*)(Wt_g + (size_t)(k+3)*NH + c0);
      #pragma unroll
      for (int r = 0; r < 8; ++r){
        const float4 ev = *(const float4*)&etile[srow + r][k];  // broadcast
        acc[r] += w0*ev.x + w1*ev.y + w2*ev.z + w3*ev.w;        // v_pk_fma_f32
      }
    }

    #pragma unroll
    for (int r = 0; r < 8; ++r){
      const int i = i0 + srow + r;
      const f32x2 li = *(const f32x2*)(lin_in + (size_t)(b*NN + i)*NH + c0);
      const f32x2 x = acc[r] + li + bj2;
      float s  = x.x + x.y;
      float s2 = x.x*x.x + x.y*x.y;
      #pragma unroll
      for (int m = 1; m <= 32; m <<= 1){
        s  += __shfl_xor(s,  m, 64);
        s2 += __shfl_xor(s2, m, 64);
      }
      const float mu  = s * (1.f/NH);
      const float var = s2 * (1.f/NH) - mu*mu;
      const float rs  = rsqrtf(var + LN_EPS);
      const int zf = (i == j) || emcol[(size_t)i*NN];
      f32x2 hh;
      hh.x = zf ? 0.f : elu1((x.x - mu)*rs*gc2.x + bec2.x);
      hh.y = zf ? 0.f : elu1((x.y - mu)*rs*gc2.y + bec2.y);
      *(f32x2*)(out_e + ebase + (size_t)i*estride + c0) = hh;
      agg += hh;
    }

    __syncthreads();
    if (t < 3){ STAGE_WRITE() }
    __syncthreads();
  }

  // per-wave agg partials -> atomicAdd into out_v (zeroed by K0a).
  // 8 atomics per element total (4 waves x 2 halves) - deterministic enough
  // (fp32 order noise ~ulp, validated protocol in round 14).
  atomicAdd(&out_v[(size_t)bj*NH + c0],     agg.x);
  atomicAdd(&out_v[(size_t)bj*NH + c0 + 1], agg.y);
}

// Combine (in place): out_v currently holds agg; finalize to
// out_v = masked v + elu(LN(agg)).
__global__ __launch_bounds__(128) void vnew_combine_kernel(
    const float* __restrict__ v,
    const int* __restrict__ v_mask,
    const float* __restrict__ g_v, const float* __restrict__ be_v,
    float* __restrict__ out_v)
{
  const int bj = blockIdx.x;   // b*NN + j
  const int c  = threadIdx.x;  // 0..127

  const float a = out_v[(size_t)bj*NH + c];

  __shared__ float red[4];
  float s = a, s2 = a*a;
  #pragma unroll
  for (int m = 1; m <= 32; m <<= 1){
    s  += __shfl_xor(s,  m, 64);
    s2 += __shfl_xor(s2, m, 64);
  }
  const int w = c >> 6;
  if ((c & 63) == 0){ red[w*2] = s; red[w*2+1] = s2; }
  __syncthreads();
  s  = red[0] + red[2];
  s2 = red[1] + red[3];

  const float mu  = s * (1.f/NH);
  const float var = s2 * (1.f/NH) - mu*mu;
  const float rs  = rsqrtf(var + LN_EPS);
  const float h   = elu1((a - mu)*rs*g_v[c] + be_v[c]);
  const int vm = v_mask[bj];
  const float vv = vm ? 0.f : v[(size_t)bj*NH + c];
  out_v[(size_t)bj*NH + c] = vv + h;
}

extern "C" void kernel_launch(void* const* d_in, const int* in_sizes, int n_in,
                              void* d_out, int out_size, void* d_ws, size_t ws_size,
                              hipStream_t stream)
{
  const float* v      = (const float*)d_in[0];
  const float* e      = (const float*)d_in[1];
  const int*   v_mask = (const int*)d_in[2];
  const int*   e_mask = (const int*)d_in[3];
  const float* W_in   = (const float*)d_in[4];
  const float* b_in   = (const float*)d_in[5];
  const float* W_out  = (const float*)d_in[6];
  const float* b_out  = (const float*)d_in[7];
  const float* W_e2e  = (const float*)d_in[8];
  const float* b_e2e  = (const float*)d_in[9];
  const float* g_e    = (const float*)d_in[10];
  const float* be_e   = (const float*)d_in[11];
  const float* g_v    = (const float*)d_in[12];
  const float* be_v   = (const float*)d_in[13];

  // ws layout: byte-identical to the round-12/14 proven-safe footprint.
  float* lin_in  = (float*)d_ws;                 // [NB*NN, NH]  512 KB
  float* lin_out = lin_in + NB*NN*NH;            // [NB*NN, NH]  512 KB
  float* Wt_g    = lin_out + NB*NN*NH;           // [NH, NH]      64 KB

  float* out_v = (float*)d_out;                  // [NB,NN,NH]
  float* out_e = out_v + (size_t)NB*NN*NH;       // [NB,NN,NN,NH]

  lin_vw_kernel<<<NB*NN, NH, 0, stream>>>(v, W_in, b_in, W_out, b_out,
                                          lin_in, lin_out, out_v);
  transpose_w_kernel<<<NH, NH, 0, stream>>>(W_e2e, Wt_g);
  nri_eout_kernel<<<2*NB*NN, 256, 0, stream>>>(e, e_mask,
                                               Wt_g, b_e2e, g_e, be_e,
                                               lin_in, lin_out,
                                               out_e, out_v);
  vnew_combine_kernel<<<NB*NN, 128, 0, stream>>>(v, v_mask, g_v, be_v, out_v);
}

// Round 18
// 160.869 us; speedup vs baseline: 2.5606x; 1.5231x over previous
//
#include <hip/hip_runtime.h>
#include <hip/hip_bf16.h>

#define NB 4
#define NN 256
#define NH 128
#define LN_EPS 1e-5f

typedef float f32x4 __attribute__((ext_vector_type(4)));
typedef short s16x8 __attribute__((ext_vector_type(8)));

__device__ __forceinline__ unsigned short f2bf(float f){
  union { float f; unsigned u; } v; v.f = f;
  unsigned u = v.u;
  u += 0x7FFFu + ((u >> 16) & 1u);   // RNE
  return (unsigned short)(u >> 16);
}

__device__ __forceinline__ s16x8 pack8(const float4 a, const float4 b){
  s16x8 r;
  r[0]=(short)f2bf(a.x); r[1]=(short)f2bf(a.y); r[2]=(short)f2bf(a.z); r[3]=(short)f2bf(a.w);
  r[4]=(short)f2bf(b.x); r[5]=(short)f2bf(b.y); r[6]=(short)f2bf(b.z); r[7]=(short)f2bf(b.w);
  return r;
}

__device__ __forceinline__ float elu1(float x){
  return x > 0.f ? x : (__expf(x) - 1.f);
}

#define LD4(p) (*(const float4*)(p))

// K0a (validated): lin_in/lin_out fp32 exact; zeroes out_v (agg accumulator).
__global__ __launch_bounds__(128) void lin_vw_kernel(
    const float* __restrict__ v,
    const float* __restrict__ W_in, const float* __restrict__ b_in,
    const float* __restrict__ W_out, const float* __restrict__ b_out,
    float* __restrict__ lin_in, float* __restrict__ lin_out,
    float* __restrict__ out_v)
{
  const int row = blockIdx.x;    // b*NN + i
  const int t = threadIdx.x;     // output col
  __shared__ float vs[NH];
  vs[t] = v[(size_t)row*NH + t];
  out_v[(size_t)row*NH + t] = 0.f;
  __syncthreads();
  const float4* wi = (const float4*)(W_in + t*NH);
  const float4* wo = (const float4*)(W_out + t*NH);
  const float4* vv = (const float4*)vs;
  float ai = b_in[t], ao = b_out[t];
  #pragma unroll
  for (int k = 0; k < NH/4; ++k){
    float4 x = vv[k];
    float4 a = wi[k], bq = wo[k];
    ai += x.x*a.x + x.y*a.y + x.z*a.z + x.w*a.w;
    ao += x.x*bq.x + x.y*bq.y + x.z*bq.z + x.w*bq.w;
  }
  lin_in[(size_t)row*NH + t]  = ai;
  lin_out[(size_t)row*NH + t] = ao;
}

// Main: one block per (b,j), 4 waves. bf16 MFMA GEMM (K=128, e@W_e2e.T) with
// RUNTIME k-layout calibration: probe MFMAs measure the relative input-
// fragment permutation pi = sigmaB^-1 o sigmaA; W packing gathers through
// pi^-1 so the dot pairs e[k] with W[k] regardless of the true HW k-layout.
// Epilogue (+lin_in +bias -> LN -> ELU -> mask -> store + agg atomics) uses
// the round-3-verified C/D attribution and validated round-14 protocol.
__global__ __launch_bounds__(256) void nri_mfma_kernel(
    const float* __restrict__ e,
    const int* __restrict__ e_mask,
    const float* __restrict__ W_e2e, const float* __restrict__ b_e2e,
    const float* __restrict__ g_e,   const float* __restrict__ be_e,
    const float* __restrict__ lin_in, const float* __restrict__ lin_out,
    float* __restrict__ out_e, float* __restrict__ out_v)
{
  const int bj   = blockIdx.x;
  const int b    = bj >> 8, j = bj & (NN-1);
  const int tid  = threadIdx.x;
  const int wave = tid >> 6;
  const int l    = tid & 63;
  const int lg   = l >> 4;
  const int lr   = l & 15;

  __shared__ s16x8 wfrag[32][64];   // [c*4+q][lane], 32 KB
  __shared__ int pi_lds[32];
  __shared__ int piinv[32];

  // ---- runtime k-layout probe (wave 0) ----
  if (wave == 0){
    const short bf1 = (short)f2bf(1.0f);
    s16x8 pa1, pa2, pb;
    #pragma unroll
    for (int e8 = 0; e8 < 8; ++e8){
      const int t = 8*lg + e8;                 // assumed k-slot of this elem
      pa1[e8] = (t == lr)      ? bf1 : (short)0;
      pa2[e8] = (t == 16 + lr) ? bf1 : (short)0;
      pb[e8]  = (short)f2bf((float)t);         // slot tag (exact in bf16)
    }
    const f32x4 z4 = (f32x4){0.f,0.f,0.f,0.f};
    f32x4 d1 = __builtin_amdgcn_mfma_f32_16x16x32_bf16(pa1, pb, z4, 0, 0, 0);
    f32x4 d2 = __builtin_amdgcn_mfma_f32_16x16x32_bf16(pa2, pb, z4, 0, 0, 0);
    if (lr == 0){
      #pragma unroll
      for (int q = 0; q < 4; ++q){
        int p1 = (int)(d1[q] + 0.5f); p1 = p1 < 0 ? 0 : (p1 > 31 ? 31 : p1);
        int p2 = (int)(d2[q] + 0.5f); p2 = p2 < 0 ? 0 : (p2 > 31 ? 31 : p2);
        pi_lds[4*lg + q]      = p1;   // pi(row) for rows 0..15
        pi_lds[16 + 4*lg + q] = p2;   // pi(16+row)
      }
    }
  }
  __syncthreads();
  if (tid < 32) piinv[tid] = tid;     // init (robust if pi degenerate)
  __syncthreads();
  if (tid < 32) piinv[pi_lds[tid]] = tid;
  __syncthreads();

  // ---- pack W fragments (B[k][col] = W[col][k]) with piinv gather ----
  #pragma unroll
  for (int cc = 0; cc < 2; ++cc){
    const int c = wave*2 + cc;
    #pragma unroll
    for (int q = 0; q < 4; ++q){
      const float* wrow = W_e2e + (size_t)(16*c + lr)*NH + 32*q;
      s16x8 wf;
      #pragma unroll
      for (int e8 = 0; e8 < 8; ++e8)
        wf[e8] = (short)f2bf(wrow[piinv[8*lg + e8]]);
      wfrag[c*4 + q][l] = wf;
    }
  }

  // per-lane column constants (col = lr + 16c)
  float bias_c[8], gc[8], bec[8];
  {
    const float* lo = lin_out + (size_t)(b*NN + j)*NH;
    #pragma unroll
    for (int c = 0; c < 8; ++c){
      const int col = lr + 16*c;
      bias_c[c] = lo[col] + b_e2e[col];
      gc[c]  = g_e[col];
      bec[c] = be_e[col];
    }
  }

  float aggacc[8];
  #pragma unroll
  for (int c = 0; c < 8; ++c) aggacc[c] = 0.f;

  __syncthreads();

  const size_t ebase   = ((size_t)b*NN)*NN*NH + (size_t)j*NH;
  const size_t estride = (size_t)NN*NH;
  const int*   emcol   = e_mask + (size_t)(b*NN)*NN + j;

  for (int it = 0; it < 4; ++it){
    const int i0 = 64*it + 16*wave;

    // A fragments: 16 e-rows (row = lr), assumed slot t = e[32q + t]
    const float* erow = e + ebase + (size_t)(i0 + lr)*estride;
    s16x8 af[4];
    #pragma unroll
    for (int q = 0; q < 4; ++q){
      float4 e0 = LD4(erow + 32*q + 8*lg);
      float4 e1 = LD4(erow + 32*q + 8*lg + 4);
      af[q] = pack8(e0, e1);
    }

    // GEMM over K=128
    f32x4 acc[8];
    #pragma unroll
    for (int c = 0; c < 8; ++c) acc[c] = (f32x4){0.f,0.f,0.f,0.f};
    #pragma unroll
    for (int q = 0; q < 4; ++q){
      #pragma unroll
      for (int c = 0; c < 8; ++c)
        acc[c] = __builtin_amdgcn_mfma_f32_16x16x32_bf16(af[q], wfrag[c*4+q][l], acc[c], 0, 0, 0);
    }

    // zero-flags per row (C/D row = 4lg + r, verified)
    int zf[4];
    #pragma unroll
    for (int r = 0; r < 4; ++r){
      const int irow = i0 + 4*lg + r;
      zf[r] = (irow == j) || emcol[(size_t)irow*NN];
    }

    // + bias + lin_in
    #pragma unroll
    for (int r = 0; r < 4; ++r){
      const float* lp = lin_in + (size_t)(b*NN + i0 + 4*lg + r)*NH + lr;
      #pragma unroll
      for (int c = 0; c < 8; ++c)
        acc[c][r] += bias_c[c] + lp[16*c];
    }

    // LN per row -> ELU -> mask -> store + agg
    #pragma unroll
    for (int r = 0; r < 4; ++r){
      float s = 0.f, s2 = 0.f;
      #pragma unroll
      for (int c = 0; c < 8; ++c){ const float xx = acc[c][r]; s += xx; s2 += xx*xx; }
      #pragma unroll
      for (int m = 1; m <= 8; m <<= 1){
        s  += __shfl_xor(s,  m, 64);
        s2 += __shfl_xor(s2, m, 64);
      }
      const float mu  = s * (1.f/NH);
      const float var = s2 * (1.f/NH) - mu*mu;
      const float rs  = rsqrtf(var + LN_EPS);
      const int irow  = i0 + 4*lg + r;
      float* orow = out_e + ebase + (size_t)irow*estride;
      #pragma unroll
      for (int c = 0; c < 8; ++c){
        const float y = (acc[c][r] - mu) * rs * gc[c] + bec[c];
        float h = elu1(y);
        h = zf[r] ? 0.f : h;
        orow[lr + 16*c] = h;
        aggacc[c] += h;
      }
    }
  }

  // agg: combine the 4 lg-groups, then one atomicAdd per col per wave
  #pragma unroll
  for (int c = 0; c < 8; ++c){
    aggacc[c] += __shfl_xor(aggacc[c], 16, 64);
    aggacc[c] += __shfl_xor(aggacc[c], 32, 64);
  }
  if (lg == 0){
    #pragma unroll
    for (int c = 0; c < 8; ++c)
      atomicAdd(&out_v[(size_t)bj*NH + lr + 16*c], aggacc[c]);
  }
}

// Combine (validated): out_v holds agg; finalize to masked v + elu(LN(agg)).
__global__ __launch_bounds__(128) void vnew_combine_kernel(
    const float* __restrict__ v,
    const int* __restrict__ v_mask,
    const float* __restrict__ g_v, const float* __restrict__ be_v,
    float* __restrict__ out_v)
{
  const int bj = blockIdx.x;
  const int c  = threadIdx.x;

  const float a = out_v[(size_t)bj*NH + c];

  __shared__ float red[4];
  float s = a, s2 = a*a;
  #pragma unroll
  for (int m = 1; m <= 32; m <<= 1){
    s  += __shfl_xor(s,  m, 64);
    s2 += __shfl_xor(s2, m, 64);
  }
  const int w = c >> 6;
  if ((c & 63) == 0){ red[w*2] = s; red[w*2+1] = s2; }
  __syncthreads();
  s  = red[0] + red[2];
  s2 = red[1] + red[3];

  const float mu  = s * (1.f/NH);
  const float var = s2 * (1.f/NH) - mu*mu;
  const float rs  = rsqrtf(var + LN_EPS);
  const float h   = elu1((a - mu)*rs*g_v[c] + be_v[c]);
  const int vm = v_mask[bj];
  const float vv = vm ? 0.f : v[(size_t)bj*NH + c];
  out_v[(size_t)bj*NH + c] = vv + h;
}

extern "C" void kernel_launch(void* const* d_in, const int* in_sizes, int n_in,
                              void* d_out, int out_size, void* d_ws, size_t ws_size,
                              hipStream_t stream)
{
  const float* v      = (const float*)d_in[0];
  const float* e      = (const float*)d_in[1];
  const int*   v_mask = (const int*)d_in[2];
  const int*   e_mask = (const int*)d_in[3];
  const float* W_in   = (const float*)d_in[4];
  const float* b_in   = (const float*)d_in[5];
  const float* W_out  = (const float*)d_in[6];
  const float* b_out  = (const float*)d_in[7];
  const float* W_e2e  = (const float*)d_in[8];
  const float* b_e2e  = (const float*)d_in[9];
  const float* g_e    = (const float*)d_in[10];
  const float* be_e   = (const float*)d_in[11];
  const float* g_v    = (const float*)d_in[12];
  const float* be_v   = (const float*)d_in[13];

  // ws: strictly within the proven-safe round-12/14 footprint.
  float* lin_in  = (float*)d_ws;                 // [NB*NN, NH]
  float* lin_out = lin_in + NB*NN*NH;            // [NB*NN, NH]

  float* out_v = (float*)d_out;                  // [NB,NN,NH]
  float* out_e = out_v + (size_t)NB*NN*NH;       // [NB,NN,NN,NH]

  lin_vw_kernel<<<NB*NN, NH, 0, stream>>>(v, W_in, b_in, W_out, b_out,
                                          lin_in, lin_out, out_v);
  nri_mfma_kernel<<<NB*NN, 256, 0, stream>>>(e, e_mask,
                                             W_e2e, b_e2e, g_e, be_e,
                                             lin_in, lin_out,
                                             out_e, out_v);
  vnew_combine_kernel<<<NB*NN, 128, 0, stream>>>(v, v_mask, g_v, be_v, out_v);
}